// Round 1
// baseline (142.426 us; speedup 1.0000x reference)
//
#include <hip/hip_runtime.h>

typedef __attribute__((ext_vector_type(8))) __bf16 bf16x8;
typedef __attribute__((ext_vector_type(4))) float f32x4;

#define MAX_ITER_N 20
#define F_TOL_F 1e-6f
#define FREE_NUM_N 64

#define BSZ 1024
#define IN_DIM 512
#define HID 1024
#define OUT_DIM 256
#define M_CON 128

// workspace layout (float offsets)
#define WS_BAR   0                         // ws[0] = done counter (merged decide)
#define WS_RES   8                         // 32 uints
#define WS_BP    48                        // 256 f32
#define WS_H1    304
#define WS_H2    (WS_H1 + 524288)
#define WS_APC   (WS_H2 + 524288)
#define WS_W0C   (WS_APC + 262144)
#define WS_W1C   (WS_W0C + 262144)
#define WS_W2C   (WS_W1C + 524288)
#define WS_WZG   (WS_W2C + 131072)
#define WS_AG    (WS_WZG + 32768)

__device__ __forceinline__ unsigned short f2bf(float f) {
    unsigned int u = __float_as_uint(f);
    u += 0x7fffu + ((u >> 16) & 1u);
    return (unsigned short)(u >> 16);
}

__device__ __forceinline__ void gload_lds16(const unsigned short* g, unsigned short* l) {
    __builtin_amdgcn_global_load_lds(
        (const __attribute__((address_space(1))) unsigned int*)(const void*)g,
        (__attribute__((address_space(3))) unsigned int*)(void*)l, 16, 0, 0);
}

// ---- prep: all bf16 conversions + bias_proj + control-region zero; 2401 blocks x 256 ----
__global__ __launch_bounds__(256) void prep_k(
    const float* __restrict__ b_primal, const float* __restrict__ W0,
    const float* __restrict__ W1, const float* __restrict__ W2,
    const float* __restrict__ Wz, const float* __restrict__ Am,
    const float* __restrict__ b_vec, const float* __restrict__ WbProj,
    float* __restrict__ ws)
{
    unsigned short* APc = (unsigned short*)(ws + WS_APC);
    unsigned short* W0c = (unsigned short*)(ws + WS_W0C);
    unsigned short* W1c = (unsigned short*)(ws + WS_W1C);
    unsigned short* W2c = (unsigned short*)(ws + WS_W2C);
    unsigned short* WzG = (unsigned short*)(ws + WS_WZG);
    unsigned short* AG  = (unsigned short*)(ws + WS_AG);
    float* bp = ws + WS_BP;

    int b = blockIdx.x;
    int tid = threadIdx.x;
    if (b >= 2400) {
        if (tid < 48) ((unsigned int*)ws)[tid] = 0u;   // done ctr + res slots (replaces memset)
        float s = 0.0f;
        for (int k = 0; k < M_CON; ++k) s += b_vec[k] * WbProj[tid * M_CON + k];
        bp[tid] = s;
        return;
    }
    const float* src; unsigned short* dst; int off;
    if (b < 512)       { src = b_primal; dst = APc; off = b; }
    else if (b < 1024) { src = W0; dst = W0c; off = b - 512; }
    else if (b < 2048) { src = W1; dst = W1c; off = b - 1024; }
    else if (b < 2304) { src = W2; dst = W2c; off = b - 2048; }
    else if (b < 2368) { src = Wz; dst = WzG; off = b - 2304; }
    else               { src = Am; dst = AG;  off = b - 2368; }
    int idx = off * 1024 + tid * 4;
    float4 v = *(const float4*)(src + idx);
    ushort4 o;
    o.x = f2bf(v.x); o.y = f2bf(v.y); o.z = f2bf(v.z); o.w = f2bf(v.w);
    *(ushort4*)(dst + idx) = o;
}

// fragment read from a Nx128 bf16 tile with 4-bit XOR granule swizzle
__device__ __forceinline__ bf16x8 frag128(const unsigned short* lds, int row, int gc) {
    int phys = gc ^ (row & 15);
    return __builtin_bit_cast(bf16x8, *(const uint4*)(lds + row * 128 + phys * 8));
}

// ---- 64x64-tile MFMA GEMM, BK=128, double-buffered; 16 MFMA/wave/chunk ----
// C[M,N] = act(A[M,K] @ B[N,K]^T + bias)
template<int K, int NTN, bool RELU, bool F32OUT>
__global__ __launch_bounds__(256, 2) void gemm64_k(
    const unsigned short* __restrict__ A,
    const unsigned short* __restrict__ B,
    const float* __restrict__ bias,
    void* __restrict__ Cv, int N_)
{
    constexpr int NCH = K / 128;
    __shared__ __align__(16) unsigned short As[2][64 * 128];
    __shared__ __align__(16) unsigned short Bs[2][64 * 128];

    const int tid = threadIdx.x;
    const int w = tid >> 6;
    const int lane = tid & 63;
    const int ln = lane & 15;
    const int q  = lane >> 4;
    const int wr = w >> 1;
    const int wc = w & 1;
    const int row0 = (blockIdx.x / NTN) * 64;
    const int col0 = (blockIdx.x % NTN) * 64;
    const unsigned short* Ab = A + row0 * K;
    const unsigned short* Bb = B + col0 * K;

    // staging: 1024 granules (16B) per matrix per buffer; wave w stages 256 (4 instrs)
    int soff[4], dbase[4];
#pragma unroll
    for (int i = 0; i < 4; ++i) {
        int P = w * 256 + i * 64 + lane;               // LDS granule (lane-linear)
        int row = P >> 4, pgc = P & 15;
        soff[i]  = row * K + (pgc ^ (row & 15)) * 8;   // XOR-permuted global source
        dbase[i] = (w * 256 + i * 64) * 8;             // shorts (wave-uniform base)
    }

    f32x4 acc[2][2];
#pragma unroll
    for (int rm = 0; rm < 2; ++rm)
#pragma unroll
        for (int cn = 0; cn < 2; ++cn)
            acc[rm][cn] = (f32x4){0.f, 0.f, 0.f, 0.f};

    // prologue: stage chunk 0 into buffer 0
#pragma unroll
    for (int i = 0; i < 4; ++i) {
        gload_lds16(Ab + soff[i], &As[0][dbase[i]]);
        gload_lds16(Bb + soff[i], &Bs[0][dbase[i]]);
    }

    for (int c = 0; c < NCH; ++c) {
        __syncthreads();                       // buf[c&1] loads drained
        if (c + 1 < NCH) {
            const unsigned short* Ak = Ab + (c + 1) * 128;
            const unsigned short* Bk = Bb + (c + 1) * 128;
            int nb = (c + 1) & 1;
#pragma unroll
            for (int i = 0; i < 4; ++i) {
                gload_lds16(Ak + soff[i], &As[nb][dbase[i]]);
                gload_lds16(Bk + soff[i], &Bs[nb][dbase[i]]);
            }
        }
        const unsigned short* Ac = As[c & 1];
        const unsigned short* Bc = Bs[c & 1];
#pragma unroll
        for (int ks = 0; ks < 4; ++ks) {
            bf16x8 af0 = frag128(Ac, wr * 32 + ln,      ks * 4 + q);
            bf16x8 af1 = frag128(Ac, wr * 32 + 16 + ln, ks * 4 + q);
            bf16x8 bf0 = frag128(Bc, wc * 32 + ln,      ks * 4 + q);
            bf16x8 bf1 = frag128(Bc, wc * 32 + 16 + ln, ks * 4 + q);
            acc[0][0] = __builtin_amdgcn_mfma_f32_16x16x32_bf16(af0, bf0, acc[0][0], 0, 0, 0);
            acc[0][1] = __builtin_amdgcn_mfma_f32_16x16x32_bf16(af0, bf1, acc[0][1], 0, 0, 0);
            acc[1][0] = __builtin_amdgcn_mfma_f32_16x16x32_bf16(af1, bf0, acc[1][0], 0, 0, 0);
            acc[1][1] = __builtin_amdgcn_mfma_f32_16x16x32_bf16(af1, bf1, acc[1][1], 0, 0, 0);
        }
    }

#pragma unroll
    for (int cn = 0; cn < 2; ++cn) {
        const int cc = col0 + wc * 32 + cn * 16 + ln;
        const float bv = bias[cc];
#pragma unroll
        for (int rm = 0; rm < 2; ++rm)
#pragma unroll
            for (int i = 0; i < 4; ++i) {
                int r = row0 + wr * 32 + rm * 16 + q * 4 + i;
                float v = acc[rm][cn][i] + bv;
                if (RELU) v = fmaxf(v, 0.0f);
                if (F32OUT) ((float*)Cv)[r * N_ + cc] = v;
                else ((unsigned short*)Cv)[r * N_ + cc] = f2bf(v);
            }
    }
}

// ---- 32x32-tile GEMM (kept for the narrow gemm3, N=256) ----
template<int K, int NTN, bool RELU, bool F32OUT>
__global__ __launch_bounds__(256, 4) void gemm32_k(
    const unsigned short* __restrict__ A,
    const unsigned short* __restrict__ B,
    const float* __restrict__ bias,
    void* __restrict__ Cv, int N_)
{
    constexpr int NCH = K / 128;
    __shared__ __align__(16) unsigned short As[2][32 * 128];
    __shared__ __align__(16) unsigned short Bs[2][32 * 128];

    const int tid = threadIdx.x;
    const int w = tid >> 6;
    const int lane = tid & 63;
    const int ln = lane & 15;
    const int q  = lane >> 4;
    const int wr = w >> 1;
    const int wc = w & 1;
    const int row0 = (blockIdx.x / NTN) * 32;
    const int col0 = (blockIdx.x % NTN) * 32;
    const unsigned short* Ab = A + row0 * K;
    const unsigned short* Bb = B + col0 * K;

    int soff[2], dbase[2];
#pragma unroll
    for (int i = 0; i < 2; ++i) {
        int P = w * 128 + i * 64 + lane;
        int row = P >> 4, pgc = P & 15;
        soff[i]  = row * K + (pgc ^ (row & 15)) * 8;
        dbase[i] = (w * 128 + i * 64) * 8;
    }

    f32x4 acc = {0.f, 0.f, 0.f, 0.f};

#pragma unroll
    for (int i = 0; i < 2; ++i) {
        gload_lds16(Ab + soff[i], &As[0][dbase[i]]);
        gload_lds16(Bb + soff[i], &Bs[0][dbase[i]]);
    }

    for (int c = 0; c < NCH; ++c) {
        __syncthreads();
        if (c + 1 < NCH) {
            const unsigned short* Ak = Ab + (c + 1) * 128;
            const unsigned short* Bk = Bb + (c + 1) * 128;
            int nb = (c + 1) & 1;
#pragma unroll
            for (int i = 0; i < 2; ++i) {
                gload_lds16(Ak + soff[i], &As[nb][dbase[i]]);
                gload_lds16(Bk + soff[i], &Bs[nb][dbase[i]]);
            }
        }
        const unsigned short* Ac = As[c & 1];
        const unsigned short* Bc = Bs[c & 1];
#pragma unroll
        for (int ks = 0; ks < 4; ++ks) {
            bf16x8 af = frag128(Ac, wr * 16 + ln, ks * 4 + q);
            bf16x8 bf = frag128(Bc, wc * 16 + ln, ks * 4 + q);
            acc = __builtin_amdgcn_mfma_f32_16x16x32_bf16(af, bf, acc, 0, 0, 0);
        }
    }

    const int c = col0 + wc * 16 + ln;
    const float bv = bias[c];
#pragma unroll
    for (int i = 0; i < 4; ++i) {
        int r = row0 + wr * 16 + q * 4 + i;
        float v = acc[i] + bv;
        if (RELU) v = fmaxf(v, 0.0f);
        if (F32OUT) ((float*)Cv)[r * N_ + c] = v;
        else ((unsigned short*)Cv)[r * N_ + c] = f2bf(v);
    }
}

// ---- 20-iter fixed-point loop + fused residual + merged decide/fallback; 64 blocks ----
__global__ __launch_bounds__(256, 1) void loop_k(
    const float* __restrict__ b_vec, const float* __restrict__ WzProj,
    float* __restrict__ out, float* __restrict__ ws)
{
    __shared__ __align__(16) unsigned char smem[16 * 257 * 4 + 64];
    unsigned int* done = (unsigned int*)ws;
    unsigned int* res = (unsigned int*)(ws + WS_RES);
    float* bp = ws + WS_BP;
    const unsigned short* WzG = (const unsigned short*)(ws + WS_WZG);
    const unsigned short* AG  = (const unsigned short*)(ws + WS_AG);
    float* outz = out + BSZ * OUT_DIM;

    const int tid  = threadIdx.x;
    const int wave = tid >> 6;
    const int lane = tid & 63;
    const int ln   = lane & 15;
    const int q    = lane >> 4;
    const int r0   = blockIdx.x * 16;

    unsigned short (*zS)[264] = (unsigned short(*)[264])smem;
    float* red = (float*)(smem + 16 * 257 * 4);

    {   // stage z0 = outz rows into zS as bf16 (vectorized)
        int row = tid >> 4;
        int c0  = (tid & 15) * 16;
        const float* src = outz + (r0 + row) * OUT_DIM + c0;
#pragma unroll
        for (int i = 0; i < 4; ++i) {
            float4 v = *(const float4*)(src + i * 4);
            ushort4 o;
            o.x = f2bf(v.x); o.y = f2bf(v.y); o.z = f2bf(v.z); o.w = f2bf(v.w);
            *(ushort4*)&zS[row][c0 + i * 4] = o;
        }
    }

    bf16x8 afr[2][8];
    float bvv[2];
#pragma unroll
    for (int mt = 0; mt < 2; ++mt) {
        int m = wave * 32 + mt * 16 + ln;
        bvv[mt] = b_vec[m];
#pragma unroll
        for (int ks = 0; ks < 8; ++ks)
            afr[mt][ks] = __builtin_bit_cast(bf16x8, *(const uint4*)(AG + m * OUT_DIM + ks * 32 + q * 8));
    }
    int colg[4];
    float bpv[4];
    bf16x8 wzfr[4][8];
#pragma unroll
    for (int nt = 0; nt < 4; ++nt) {
        colg[nt] = wave * 64 + nt * 16 + ln;
        bpv[nt]  = bp[colg[nt]];
#pragma unroll
        for (int ks = 0; ks < 8; ++ks)
            wzfr[nt][ks] = __builtin_bit_cast(bf16x8, *(const uint4*)(WzG + colg[nt] * OUT_DIM + ks * 32 + q * 8));
    }
    __syncthreads();

    bf16x8 zfr[8];
#pragma unroll
    for (int ks = 0; ks < 8; ++ks)
        zfr[ks] = __builtin_bit_cast(bf16x8, *(const uint4*)&zS[ln][ks * 32 + q * 8]);

    const f32x4 zero4 = {0.f, 0.f, 0.f, 0.f};

    for (int t = 1; t <= MAX_ITER_N; ++t) {
        // fused: acc = z_{t-1} @ Wz^T  (32 MFMA)  +  acc2 = z_{t-1} @ A^T (16 MFMA, t>1)
        f32x4 acc[4];
        f32x4 acc2[2];
#pragma unroll
        for (int nt = 0; nt < 4; ++nt) acc[nt] = zero4;
        acc2[0] = zero4; acc2[1] = zero4;
#pragma unroll
        for (int ks = 0; ks < 8; ++ks) {
#pragma unroll
            for (int nt = 0; nt < 4; ++nt)
                acc[nt] = __builtin_amdgcn_mfma_f32_16x16x32_bf16(zfr[ks], wzfr[nt][ks], acc[nt], 0, 0, 0);
            if (t > 1) {
#pragma unroll
                for (int mt = 0; mt < 2; ++mt)
                    acc2[mt] = __builtin_amdgcn_mfma_f32_16x16x32_bf16(zfr[ks], afr[mt][ks], acc2[mt], 0, 0, 0);
            }
        }
        float vals[4][4];
#pragma unroll
        for (int nt = 0; nt < 4; ++nt)
#pragma unroll
            for (int i = 0; i < 4; ++i) {
                float v = acc[nt][i] + bpv[nt];
                if (colg[nt] >= FREE_NUM_N) v = fmaxf(v, 0.0f);
                vals[nt][i] = v;
            }
        if (t > 1) {   // residual of z_{t-1} -> res[t-2]
            float lmax = 0.0f;
#pragma unroll
            for (int mt = 0; mt < 2; ++mt)
#pragma unroll
                for (int i = 0; i < 4; ++i)
                    lmax = fmaxf(lmax, fabsf(acc2[mt][i] - bvv[mt]));
#pragma unroll
            for (int off = 32; off > 0; off >>= 1)
                lmax = fmaxf(lmax, __shfl_xor(lmax, off));
            if (lane == 0) red[wave] = lmax;
        }
        if (t == MAX_ITER_N) {
#pragma unroll
            for (int nt = 0; nt < 4; ++nt)
#pragma unroll
                for (int i = 0; i < 4; ++i)
                    out[(r0 + q * 4 + i) * OUT_DIM + colg[nt]] = vals[nt][i];
        }
        __syncthreads();   // S1: reads of zS done + red written
        if (t > 1 && tid == 0) {
            float bm = fmaxf(fmaxf(red[0], red[1]), fmaxf(red[2], red[3]));
            atomicMax(res + (t - 2), __float_as_uint(bm));
        }
#pragma unroll
        for (int nt = 0; nt < 4; ++nt)
#pragma unroll
            for (int i = 0; i < 4; ++i)
                zS[q * 4 + i][colg[nt]] = f2bf(vals[nt][i]);
        __syncthreads();   // S2: zS = z_t complete
#pragma unroll
        for (int ks = 0; ks < 8; ++ks)
            zfr[ks] = __builtin_bit_cast(bf16x8, *(const uint4*)&zS[ln][ks * 32 + q * 8]);
    }

    {   // final residual of z_20 -> res[19], then signal done
        f32x4 acc2[2];
        acc2[0] = zero4; acc2[1] = zero4;
#pragma unroll
        for (int ks = 0; ks < 8; ++ks)
#pragma unroll
            for (int mt = 0; mt < 2; ++mt)
                acc2[mt] = __builtin_amdgcn_mfma_f32_16x16x32_bf16(zfr[ks], afr[mt][ks], acc2[mt], 0, 0, 0);
        float lmax = 0.0f;
#pragma unroll
        for (int mt = 0; mt < 2; ++mt)
#pragma unroll
            for (int i = 0; i < 4; ++i)
                lmax = fmaxf(lmax, fabsf(acc2[mt][i] - bvv[mt]));
#pragma unroll
        for (int off = 32; off > 0; off >>= 1)
            lmax = fmaxf(lmax, __shfl_xor(lmax, off));
        if (lane == 0) red[wave] = lmax;
        __syncthreads();
        if (tid == 0) {
            float bm = fmaxf(fmaxf(red[0], red[1]), fmaxf(red[2], red[3]));
            atomicMax(res + (MAX_ITER_N - 1), __float_as_uint(bm));
            __threadfence();
            atomicAdd(done, 1u);
            while (__hip_atomic_load(done, __ATOMIC_ACQUIRE, __HIP_MEMORY_SCOPE_AGENT) < 64u)
                __builtin_amdgcn_s_sleep(2);
        }
        __syncthreads();   // all blocks' res[] contributions complete
    }

    // ---- merged decide: replay reference stopping rule ----
    int T;
    {
        float rv = 1e30f;
        if (tid < MAX_ITER_N)
            rv = __uint_as_float(__hip_atomic_load(res + tid, __ATOMIC_ACQUIRE, __HIP_MEMORY_SCOPE_AGENT));
        if (tid < 64) {
            unsigned long long m = __ballot((tid < MAX_ITER_N) && !(rv > F_TOL_F));
            if (tid == 0) red[0] = (float)(m ? (int)__ffsll(m) : MAX_ITER_N);
        }
        __syncthreads();
        T = (int)red[0];
    }
    if (blockIdx.x == 0 && tid == 0)
        out[2 * BSZ * OUT_DIM] = (float)(T + 1);    // curr_iter
    if (T >= MAX_ITER_N) return;                    // hot path

    // ---- cold fp32 fallback for this block's 16 rows ----
    float (*zF)[257] = (float(*)[257])smem;
    {
        const int row = tid >> 4;
        const int c0 = (tid & 15) * 16;
        for (int i = 0; i < 16; ++i)
            zF[row][c0 + i] = outz[(r0 + row) * OUT_DIM + c0 + i];
        __syncthreads();
        const int j = tid;
        const float bj = bp[j];
        for (int t = 0; t < T; ++t) {
            float acc[16] = {};
            for (int k = 0; k < OUT_DIM; ++k) {
                float wv = WzProj[j * OUT_DIM + k];
#pragma unroll
                for (int r = 0; r < 16; ++r) acc[r] += zF[r][k] * wv;
            }
            __syncthreads();
#pragma unroll
            for (int r = 0; r < 16; ++r) {
                float v = acc[r] + bj;
                if (j >= FREE_NUM_N) v = fmaxf(v, 0.0f);
                zF[r][j] = v;
            }
            __syncthreads();
        }
        for (int i = 0; i < 16; ++i)
            out[(r0 + row) * OUT_DIM + c0 + i] = zF[row][c0 + i];
    }
}

extern "C" void kernel_launch(void* const* d_in, const int* in_sizes, int n_in,
                              void* d_out, int out_size, void* d_ws, size_t ws_size,
                              hipStream_t stream) {
    const float* b_primal = (const float*)d_in[0];
    const float* W0     = (const float*)d_in[1];
    const float* b0     = (const float*)d_in[2];
    const float* W1     = (const float*)d_in[3];
    const float* b1     = (const float*)d_in[4];
    const float* W2     = (const float*)d_in[5];
    const float* b2     = (const float*)d_in[6];
    const float* Amat   = (const float*)d_in[7];
    const float* b_vec  = (const float*)d_in[8];
    const float* WzProj = (const float*)d_in[9];
    const float* WbProj = (const float*)d_in[10];
    float* out = (float*)d_out;
    float* ws  = (float*)d_ws;

    unsigned short* h1c = (unsigned short*)(ws + WS_H1);
    unsigned short* h2c = (unsigned short*)(ws + WS_H2);
    unsigned short* APc = (unsigned short*)(ws + WS_APC);
    unsigned short* W0c = (unsigned short*)(ws + WS_W0C);
    unsigned short* W1c = (unsigned short*)(ws + WS_W1C);
    unsigned short* W2c = (unsigned short*)(ws + WS_W2C);
    float* outz = out + BSZ * OUT_DIM;

    hipLaunchKernelGGL(prep_k, dim3(2401), dim3(256), 0, stream,
                       b_primal, W0, W1, W2, WzProj, Amat, b_vec, WbProj, ws);

    hipLaunchKernelGGL((gemm64_k<IN_DIM, 16, true, false>), dim3(256), dim3(256), 0, stream,
                       APc, W0c, b0, (void*)h1c, HID);
    hipLaunchKernelGGL((gemm64_k<HID, 16, true, false>), dim3(256), dim3(256), 0, stream,
                       h1c, W1c, b1, (void*)h2c, HID);
    hipLaunchKernelGGL((gemm32_k<HID, 8, false, true>), dim3(256), dim3(256), 0, stream,
                       h2c, W2c, b2, (void*)outz, OUT_DIM);

    hipLaunchKernelGGL(loop_k, dim3(64), dim3(256), 0, stream, b_vec, WzProj, out, ws);
}